// Round 9
// baseline (499.474 us; speedup 1.0000x reference)
//
#include <hip/hip_runtime.h>
#include <stdint.h>

typedef unsigned short ushort_t;
typedef __attribute__((ext_vector_type(8))) short bf16x8;
typedef __attribute__((ext_vector_type(4))) float f32x4;
typedef __attribute__((ext_vector_type(16))) float f32x16;
typedef __attribute__((ext_vector_type(4))) unsigned short u16x4;

#define B_ 2
#define T_ 2048
#define D_ 2048
#define H_ 16
#define HD_ 128
#define BT_ 4096

__device__ __forceinline__ ushort_t f2bf(float f) {
  unsigned u = __float_as_uint(f);
  u += 0x7FFFu + ((u >> 16) & 1u);   // RNE
  return (ushort_t)(u >> 16);
}

__device__ __forceinline__ float b2f(ushort_t u) {
  return __uint_as_float((unsigned)u << 16);
}

// pack two f32 -> u32 of 2 bf16 (RNE), low = first arg [T12 primitive, m214v22]
__device__ __forceinline__ unsigned cvtpk(float lo, float hi) {
  unsigned r;
  asm("v_cvt_pk_bf16_f32 %0, %1, %2" : "=v"(r) : "v"(lo), "v"(hi));
  return r;
}

__device__ __forceinline__ bf16x8 mk8(unsigned a, unsigned b, unsigned c, unsigned d) {
  union { unsigned u[4]; bf16x8 v; } x;
  x.u[0] = a; x.u[1] = b; x.u[2] = c; x.u[3] = d;
  return x.v;
}

__device__ __forceinline__ void async16(const void* g, void* l) {
  __builtin_amdgcn_global_load_lds(
      (const __attribute__((address_space(1))) unsigned int*)g,
      (__attribute__((address_space(3))) unsigned int*)l, 16, 0, 0);
}

// ---------------- elementwise cast x -> bf16 ----------------
__global__ void k_cast_x(const float* __restrict__ in, ushort_t* __restrict__ out) {
  int i = blockIdx.x * 256 + threadIdx.x;          // 4 elements per thread
  float4 v = ((const float4*)in)[i];
  u16x4 r = { f2bf(v.x), f2bf(v.y), f2bf(v.z), f2bf(v.w) };
  ((u16x4*)out)[i] = r;
}

// ---------------- fused weight transpose+cast x5: w[K][N] f32 -> wt[N][K] bf16 ----------------
__global__ void k_twT5(const float* __restrict__ wa, const float* __restrict__ wb,
                       const float* __restrict__ wc, const float* __restrict__ wd,
                       const float* __restrict__ we,
                       ushort_t* __restrict__ ta, ushort_t* __restrict__ tb,
                       ushort_t* __restrict__ tc, ushort_t* __restrict__ td,
                       ushort_t* __restrict__ te) {
  const float* w; ushort_t* wt;
  switch (blockIdx.z) {
    case 0: w = wa; wt = ta; break;
    case 1: w = wb; wt = tb; break;
    case 2: w = wc; wt = tc; break;
    case 3: w = wd; wt = td; break;
    default: w = we; wt = te; break;
  }
  __shared__ float tile[32][33];
  int tx = threadIdx.x, ty = threadIdx.y;
  int x = blockIdx.x * 32 + tx;        // N index
  int y0 = blockIdx.y * 32;            // K index
#pragma unroll
  for (int k = 0; k < 4; ++k)
    tile[ty + k * 8][tx] = w[(size_t)(y0 + ty + k * 8) * D_ + x];
  __syncthreads();
  int ox = blockIdx.y * 32 + tx;       // K contiguous on write
  int oy0 = blockIdx.x * 32;           // N
#pragma unroll
  for (int k = 0; k < 4; ++k)
    wt[(size_t)(oy0 + ty + k * 8) * D_ + ox] = f2bf(tile[tx][ty + k * 8]);
}

// ---------------- fused QKV GEMM: C[4096][6144] = xb * [wqT;wkT;wvT]^T + bias ----------------
// wqT/wkT/wvT are contiguous in ws -> one B matrix of 6144 rows. Region (per 2048
// output cols) selects bias + destination: q->qf fp32, k->kf fp32, v->vb bf16.
// Same proven 512-thr / 8-wave / 128x128 / BK=64 / dbuf / 1-barrier structure.
__global__ __launch_bounds__(512) void k_gemm_qkv(
    const ushort_t* __restrict__ A, const ushort_t* __restrict__ Bt,
    const float* __restrict__ bq, const float* __restrict__ bk,
    const float* __restrict__ bv, float* __restrict__ qf,
    float* __restrict__ kf, ushort_t* __restrict__ vb) {
  __shared__ __align__(16) short As[2][128 * 64];
  __shared__ __align__(16) short Bs[2][128 * 64];
  const int tid = threadIdx.x;
  const int wid = tid >> 6, lane = tid & 63;
  const int l15 = lane & 15, kq = lane >> 4;
  const int m0 = (wid >> 2) * 64, n0 = (wid & 3) * 32;
  const int tileM = blockIdx.y * 128, tileN = blockIdx.x * 128;
  const int region = tileN >> 11;                  // 0:q 1:k 2:v
  const float* bias = region == 0 ? bq : (region == 1 ? bk : bv);

  f32x4 acc[4][2];
#pragma unroll
  for (int i = 0; i < 4; ++i)
#pragma unroll
    for (int j = 0; j < 2; ++j) acc[i][j] = (f32x4){0.f, 0.f, 0.f, 0.f};

  auto stage = [&](int sbuf, int k0) {
#pragma unroll
    for (int rr = 0; rr < 2; ++rr) {
      int c = rr * 512 + tid;
      int row = c >> 3, p = c & 7;
      int gc = p ^ (row & 7);
      async16(A + (size_t)(tileM + row) * D_ + k0 + gc * 8,
              &As[sbuf][(rr * 512 + wid * 64) * 8]);
      async16(Bt + (size_t)(tileN + row) * D_ + k0 + gc * 8,
              &Bs[sbuf][(rr * 512 + wid * 64) * 8]);
    }
  };

  stage(0, 0);
  for (int k0 = 0; k0 < D_; k0 += 64) {
    const int buf = (k0 >> 6) & 1;
    __asm__ volatile("s_waitcnt vmcnt(0)" ::: "memory");
    __builtin_amdgcn_s_barrier();
    if (k0 + 64 < D_) stage(buf ^ 1, k0 + 64);
#pragma unroll
    for (int half = 0; half < 2; ++half) {
      bf16x8 a[4], b[2];
#pragma unroll
      for (int i = 0; i < 4; ++i) {
        int row = m0 + i * 16 + l15;
        a[i] = *(const bf16x8*)&As[buf][row * 64 + ((half * 4 + kq) ^ (row & 7)) * 8];
      }
#pragma unroll
      for (int j = 0; j < 2; ++j) {
        int row = n0 + j * 16 + l15;
        b[j] = *(const bf16x8*)&Bs[buf][row * 64 + ((half * 4 + kq) ^ (row & 7)) * 8];
      }
#pragma unroll
      for (int i = 0; i < 4; ++i)
#pragma unroll
        for (int j = 0; j < 2; ++j)
          acc[i][j] = __builtin_amdgcn_mfma_f32_16x16x32_bf16(a[i], b[j], acc[i][j], 0, 0, 0);
    }
  }

#pragma unroll
  for (int i = 0; i < 4; ++i) {
#pragma unroll
    for (int j = 0; j < 2; ++j) {
#pragma unroll
      for (int r = 0; r < 4; ++r) {
        int gm = tileM + m0 + i * 16 + kq * 4 + r;
        int gn = tileN + n0 + j * 16 + l15;
        int gnl = gn & 2047;                       // col within region
        float val = acc[i][j][r] + bias[gnl];
        size_t idx = (size_t)gm * D_ + gnl;
        if (region == 0) qf[idx] = val;
        else if (region == 1) kf[idx] = val;
        else vb[idx] = f2bf(val);
      }
    }
  }
}

// ---------------- GEMM (wo/wg): C = A * Bt^T + bias ----------------
// EPI 2: store fp32 + bf16.  3: gate (out = aux * sigmoid(val))
template <int EPI>
__global__ __launch_bounds__(512) void k_gemm(
    const ushort_t* __restrict__ A, const ushort_t* __restrict__ Bt,
    const float* __restrict__ bias, float* __restrict__ outF,
    ushort_t* __restrict__ outB, const float* __restrict__ aux) {
  __shared__ __align__(16) short As[2][128 * 64];
  __shared__ __align__(16) short Bs[2][128 * 64];
  const int tid = threadIdx.x;
  const int wid = tid >> 6, lane = tid & 63;
  const int l15 = lane & 15, kq = lane >> 4;
  const int m0 = (wid >> 2) * 64, n0 = (wid & 3) * 32;
  const int tileM = blockIdx.y * 128, tileN = blockIdx.x * 128;

  f32x4 acc[4][2];
#pragma unroll
  for (int i = 0; i < 4; ++i)
#pragma unroll
    for (int j = 0; j < 2; ++j) acc[i][j] = (f32x4){0.f, 0.f, 0.f, 0.f};

  auto stage = [&](int sbuf, int k0) {
#pragma unroll
    for (int rr = 0; rr < 2; ++rr) {
      int c = rr * 512 + tid;
      int row = c >> 3, p = c & 7;
      int gc = p ^ (row & 7);
      async16(A + (size_t)(tileM + row) * D_ + k0 + gc * 8,
              &As[sbuf][(rr * 512 + wid * 64) * 8]);
      async16(Bt + (size_t)(tileN + row) * D_ + k0 + gc * 8,
              &Bs[sbuf][(rr * 512 + wid * 64) * 8]);
    }
  };

  stage(0, 0);
  for (int k0 = 0; k0 < D_; k0 += 64) {
    const int buf = (k0 >> 6) & 1;
    __asm__ volatile("s_waitcnt vmcnt(0)" ::: "memory");
    __builtin_amdgcn_s_barrier();
    if (k0 + 64 < D_) stage(buf ^ 1, k0 + 64);
#pragma unroll
    for (int half = 0; half < 2; ++half) {
      bf16x8 a[4], b[2];
#pragma unroll
      for (int i = 0; i < 4; ++i) {
        int row = m0 + i * 16 + l15;
        a[i] = *(const bf16x8*)&As[buf][row * 64 + ((half * 4 + kq) ^ (row & 7)) * 8];
      }
#pragma unroll
      for (int j = 0; j < 2; ++j) {
        int row = n0 + j * 16 + l15;
        b[j] = *(const bf16x8*)&Bs[buf][row * 64 + ((half * 4 + kq) ^ (row & 7)) * 8];
      }
#pragma unroll
      for (int i = 0; i < 4; ++i)
#pragma unroll
        for (int j = 0; j < 2; ++j)
          acc[i][j] = __builtin_amdgcn_mfma_f32_16x16x32_bf16(a[i], b[j], acc[i][j], 0, 0, 0);
    }
  }

#pragma unroll
  for (int i = 0; i < 4; ++i) {
#pragma unroll
    for (int j = 0; j < 2; ++j) {
#pragma unroll
      for (int r = 0; r < 4; ++r) {
        int gm = tileM + m0 + i * 16 + kq * 4 + r;
        int gn = tileN + n0 + j * 16 + l15;
        size_t idx = (size_t)gm * D_ + gn;
        float val = acc[i][j][r] + bias[gn];
        if (EPI == 2) {
          outF[idx] = val; outB[idx] = f2bf(val);
        } else {
          float sg = 1.f / (1.f + __expf(-val));
          outF[idx] = aux[idx] * sg;
        }
      }
    }
  }
}

// ---------------- fused RMSNorm (full D) + RoPE, fp32 in -> bf16 out (x oscale) ----------------
__global__ void k_normrope(const float* __restrict__ in, const float* __restrict__ g,
                           const float* __restrict__ cs, const float* __restrict__ sn,
                           ushort_t* __restrict__ out, float oscale) {
  const int row = blockIdx.x;            // 0..4095 = b*T + t
  const int t = row & (T_ - 1);
  const float* x = in + (size_t)row * D_;
  const int tid = threadIdx.x;
  float ss = 0.f;
#pragma unroll
  for (int i = tid; i < 512; i += 256) {
    float4 v = ((const float4*)x)[i];
    ss += v.x * v.x + v.y * v.y + v.z * v.z + v.w * v.w;
  }
#pragma unroll
  for (int off = 1; off < 64; off <<= 1) ss += __shfl_xor(ss, off, 64);
  __shared__ float part[4];
  if ((tid & 63) == 0) part[tid >> 6] = ss;
  __syncthreads();
  float rstd = rsqrtf((part[0] + part[1] + part[2] + part[3]) * (1.f / (float)D_) + 1e-6f);
  rstd *= oscale;                        // fold attention scale*log2e into Q
#pragma unroll
  for (int p = tid; p < 1024; p += 256) {
    int head = p >> 6, i = p & 63;
    int e1 = head * HD_ + i, e2 = e1 + 64;
    float x1 = x[e1] * rstd * g[e1];
    float x2 = x[e2] * rstd * g[e2];
    float c = cs[t * 64 + i], s = sn[t * 64 + i];
    out[(size_t)row * D_ + e1] = f2bf(x1 * c - s * x2);
    out[(size_t)row * D_ + e2] = f2bf(x2 * c + s * x1);
  }
}

// ---------------- V transpose per head: v[b][t][h*128+d] -> vt[bh][d][t] ----------------
__global__ void k_tv(const ushort_t* __restrict__ v, ushort_t* __restrict__ vt) {
  __shared__ ushort_t tile[32][33];
  int bh = blockIdx.z, b = bh >> 4, h = bh & 15;
  int tx = threadIdx.x, ty = threadIdx.y;
  int d = blockIdx.x * 32 + tx;
  int t0 = blockIdx.y * 32;
#pragma unroll
  for (int k = 0; k < 4; ++k)
    tile[ty + k * 8][tx] = v[(size_t)(b * T_ + t0 + ty + k * 8) * D_ + h * HD_ + d];
  __syncthreads();
  int ot = t0 + tx;
  int od0 = blockIdx.x * 32;
#pragma unroll
  for (int k = 0; k < 4; ++k)
    vt[((size_t)bh * HD_ + od0 + ty + k * 8) * T_ + ot] = tile[tx][ty + k * 8];
}

// ---------------- flash v11: KV-split x2 (flash-decoding). Grid 1024 -> 16 waves/CU
// (was 8, grid-capped). Fixed-max softmax makes the merge exact: partials combine as
// (num0+num1)/(l0+l1) -- no max-rescale. Numerator stored bf16 (P already bf16; one
// more RNE rounding << error budget). Single-s QK chain (R8's sA/sB VALU cost
// reverted); verified permlane in-register P transpose kept. ----------------
__global__ __launch_bounds__(256) void k_flash(
    const ushort_t* __restrict__ Q, const ushort_t* __restrict__ K,
    const ushort_t* __restrict__ Vt, ushort_t* __restrict__ On0,
    ushort_t* __restrict__ On1, float* __restrict__ Lf) {
  __shared__ __align__(16) short Ks[2][32 * 128];   // [buf][key][d]   8 KB each
  __shared__ __align__(16) short Vs[2][128 * 32];   // [buf][d][key]   8 KB each

  const int tid = threadIdx.x;
  const int wv = tid >> 6, lane = tid & 63;
  const int l31 = lane & 31, hi = lane >> 5;
  const int flat = blockIdx.x;                       // 1024 blocks
  const int swz = (flat & 7) * 128 + (flat >> 3);    // bijective XCD chunking (1024=8*128)
  const int bh = swz >> 5, b = bh >> 4, h = bh & 15;
  const int rem = swz & 31;
  const int split = rem >> 4;                        // 0: keys 0..1023, 1: keys 1024..2047
  const int q0 = (rem & 15) * 128;
  const int kbase = split * 32;                      // K-tile index base
  ushort_t* __restrict__ On = split ? On1 : On0;

  const ushort_t* kp[2];
  const ushort_t* vp[2];
#pragma unroll
  for (int rr = 0; rr < 2; ++rr) {
    int c = rr * 256 + tid;
    int krow = c >> 4, kc = (c & 15) ^ (krow & 15);       // 16 chunks/row (128 d)
    kp[rr] = K + (size_t)(b * T_ + krow) * D_ + h * HD_ + kc * 8;
    int drow = c >> 2, vc = (c & 3) ^ ((drow >> 1) & 3);  // 4 chunks/row (32 keys)
    vp[rr] = Vt + ((size_t)bh * HD_ + drow) * T_ + vc * 8;
  }

  // Q B-frags in registers: wave owns 32 q-rows (q0 + wv*32 + l31); scale pre-folded.
  bf16x8 qa[8];
  {
    const ushort_t* qp = Q + (size_t)(b * T_ + q0 + wv * 32 + l31) * D_ + h * HD_ + hi * 8;
#pragma unroll
    for (int kk = 0; kk < 8; ++kk) qa[kk] = *(const bf16x8*)(qp + kk * 16);
  }

  f32x16 o[4];
#pragma unroll
  for (int dt = 0; dt < 4; ++dt)
#pragma unroll
    for (int e = 0; e < 16; ++e) o[dt][e] = 0.f;
  float lsum = 0.f;

  // prologue: stage K(kbase), V(kbase) into buf 0
#pragma unroll
  for (int rr = 0; rr < 2; ++rr)
    async16(kp[rr] + (size_t)kbase * 32 * D_, &Ks[0][(rr * 256 + wv * 64) * 8]);
#pragma unroll
  for (int rr = 0; rr < 2; ++rr)
    async16(vp[rr] + (size_t)kbase * 32, &Vs[0][(rr * 256 + wv * 64) * 8]);

  for (int it = 0; it < 32; ++it) {
    const int kt = kbase + it;
    const int buf = it & 1;
    __asm__ volatile("s_waitcnt vmcnt(0)" ::: "memory");
    __builtin_amdgcn_s_barrier();

    if (it + 1 < 32) {
#pragma unroll
      for (int rr = 0; rr < 2; ++rr)
        async16(kp[rr] + (size_t)(kt + 1) * 32 * D_, &Ks[buf ^ 1][(rr * 256 + wv * 64) * 8]);
#pragma unroll
      for (int rr = 0; rr < 2; ++rr)
        async16(vp[rr] + (size_t)(kt + 1) * 32, &Vs[buf ^ 1][(rr * 256 + wv * 64) * 8]);
    }

    // S^T = K*Q^T (A=K rows=keys, B=Q cols=q): D col = q = l31 (lane-local)
    f32x16 s;
#pragma unroll
    for (int e = 0; e < 16; ++e) s[e] = 0.f;
    __builtin_amdgcn_s_setprio(1);
#pragma unroll
    for (int kk = 0; kk < 8; ++kk) {
      bf16x8 kf = *(const bf16x8*)&Ks[buf][l31 * 128 + (((kk << 1) + hi) ^ (l31 & 15)) * 8];
      s = __builtin_amdgcn_mfma_f32_32x32x16_bf16(kf, qa[kk], s, 0, 0, 0);
    }
    __builtin_amdgcn_s_setprio(0);

    // fixed-max softmax (exp2 domain): lane-local partials, pack to bf16 words
    unsigned w[8];
#pragma unroll
    for (int j = 0; j < 8; ++j) {
      float pa = __builtin_amdgcn_exp2f(s[2 * j]);
      float pb = __builtin_amdgcn_exp2f(s[2 * j + 1]);
      lsum += pa + pb;
      w[j] = cvtpk(pa, pb);
    }

    // in-register P transpose (verified R8): lo/hi half-wave exchange
    auto r02 = __builtin_amdgcn_permlane32_swap(w[0], w[2], false, false);
    auto r13 = __builtin_amdgcn_permlane32_swap(w[1], w[3], false, false);
    auto r46 = __builtin_amdgcn_permlane32_swap(w[4], w[6], false, false);
    auto r57 = __builtin_amdgcn_permlane32_swap(w[5], w[7], false, false);
    bf16x8 pf0 = mk8(r02[0], r13[0], r02[1], r13[1]);
    bf16x8 pf1 = mk8(r46[0], r57[0], r46[1], r57[1]);

    // O += P * V
    __builtin_amdgcn_s_setprio(1);
#pragma unroll
    for (int dt = 0; dt < 4; ++dt) {
      int vrow = dt * 32 + l31;
      bf16x8 vf0 = *(const bf16x8*)&Vs[buf][vrow * 32 + ((hi) ^ ((vrow >> 1) & 3)) * 8];
      o[dt] = __builtin_amdgcn_mfma_f32_32x32x16_bf16(pf0, vf0, o[dt], 0, 0, 0);
      bf16x8 vf1 = *(const bf16x8*)&Vs[buf][vrow * 32 + ((2 + hi) ^ ((vrow >> 1) & 3)) * 8];
      o[dt] = __builtin_amdgcn_mfma_f32_32x32x16_bf16(pf1, vf1, o[dt], 0, 0, 0);
    }
    __builtin_amdgcn_s_setprio(0);
  }

  // partial denominator for q=l31 over this split's keys
  lsum += __shfl_xor(lsum, 32, 64);
  if (hi == 0)
    Lf[split * (32 * 2048) + bh * 2048 + q0 + wv * 32 + l31] = lsum;

  // store raw numerator (bf16), no normalization
#pragma unroll
  for (int r = 0; r < 16; ++r) {
    int qrow = (r & 3) + 8 * (r >> 2) + 4 * hi;
    size_t row = (size_t)(b * T_ + q0 + wv * 32 + qrow);
#pragma unroll
    for (int dt = 0; dt < 4; ++dt)
      On[row * D_ + h * HD_ + dt * 32 + l31] = f2bf(o[dt][r]);
  }
}

// ---------------- merge: out = (num0 + num1) / (l0 + l1) ----------------
__global__ void k_merge(const ushort_t* __restrict__ On0, const ushort_t* __restrict__ On1,
                        const float* __restrict__ Lf, ushort_t* __restrict__ out) {
  int g = blockIdx.x * 256 + threadIdx.x;          // 8 elems per thread
  int base = g * 8;
  int row = base >> 11;                            // b*T + q
  int col = base & 2047;
  int h = col >> 7;
  int b = row >> 11;
  int q = row & 2047;
  int li = (b * 16 + h) * 2048 + q;
  float inv = 1.f / (Lf[li] + Lf[32 * 2048 + li]);
  bf16x8 a = *(const bf16x8*)&On0[base];
  bf16x8 c = *(const bf16x8*)&On1[base];
  union { ushort_t u[8]; bf16x8 v; } r;
#pragma unroll
  for (int e = 0; e < 8; ++e)
    r.u[e] = f2bf((b2f((ushort_t)a[e]) + b2f((ushort_t)c[e])) * inv);
  *(bf16x8*)&out[base] = r.v;
}

// ---------------- launch ----------------
extern "C" void kernel_launch(void* const* d_in, const int* in_sizes, int n_in,
                              void* d_out, int out_size, void* d_ws, size_t ws_size,
                              hipStream_t stream) {
  const float* x  = (const float*)d_in[0];
  const float* cs = (const float*)d_in[1];
  const float* sn = (const float*)d_in[2];
  const float* wq = (const float*)d_in[3];
  const float* bq = (const float*)d_in[4];
  const float* wk = (const float*)d_in[5];
  const float* bk = (const float*)d_in[6];
  const float* wv = (const float*)d_in[7];
  const float* bv = (const float*)d_in[8];
  const float* gq = (const float*)d_in[9];
  const float* gk = (const float*)d_in[10];
  const float* wo = (const float*)d_in[11];
  const float* bo = (const float*)d_in[12];
  const float* wg = (const float*)d_in[13];
  const float* bg = (const float*)d_in[14];

  char* ws = (char*)d_ws;
  const size_t SZ_BTD_BF = (size_t)BT_ * D_ * 2;   // 16 MB
  const size_t SZ_DD_BF  = (size_t)D_ * D_ * 2;    //  8 MB
  const size_t SZ_BTD_F  = (size_t)BT_ * D_ * 4;   // 32 MB

  size_t off = 0;
  ushort_t* xb  = (ushort_t*)(ws + off); off += SZ_BTD_BF;        // aliased as attn later
  ushort_t* wqT = (ushort_t*)(ws + off); off += SZ_DD_BF;         // wqT/wkT/wvT contiguous:
  ushort_t* wkT = (ushort_t*)(ws + off); off += SZ_DD_BF;         //   one 6144-row B matrix
  ushort_t* wvT = (ushort_t*)(ws + off); off += SZ_DD_BF;
  ushort_t* woT = (ushort_t*)(ws + off); off += SZ_DD_BF;
  ushort_t* wgT = (ushort_t*)(ws + off); off += SZ_DD_BF;
  float*    qf  = (float*)(ws + off);    off += SZ_BTD_F;         // aliased On0/On1, then outf
  float*    kf  = (float*)(ws + off);    off += SZ_BTD_F;         // aliased as outb later
  ushort_t* vb  = (ushort_t*)(ws + off); off += SZ_BTD_BF;
  ushort_t* qb  = (ushort_t*)(ws + off); off += SZ_BTD_BF;
  ushort_t* kb  = (ushort_t*)(ws + off); off += SZ_BTD_BF;
  ushort_t* vt  = (ushort_t*)(ws + off); off += SZ_BTD_BF;
  float*    Lf  = (float*)(ws + off);    off += 2 * 32 * 2048 * 4; // 512 KB lsums
  ushort_t* attn = xb;            // xb dead after QKV GEMM
  float*    outf = qf;            // qf dead after norm_rope(q); On dead after merge
  ushort_t* outb = (ushort_t*)kf; // kf dead after norm_rope(k)
  ushort_t* On0 = (ushort_t*)qf;                   // 16 MB
  ushort_t* On1 = On0 + (size_t)BT_ * D_;          // 16 MB (fits in qf's 32 MB)

  const float cl2 = 0.08838834764831845f * 1.4426950408889634f;  // 1/sqrt(128)*log2e

  k_cast_x<<<8192, 256, 0, stream>>>(x, xb);
  k_twT5<<<dim3(64, 64, 5), dim3(32, 8), 0, stream>>>(wq, wk, wv, wo, wg,
                                                      wqT, wkT, wvT, woT, wgT);

  k_gemm_qkv<<<dim3(48, 32), 512, 0, stream>>>(xb, wqT, bq, bk, bv, qf, kf, vb);

  k_normrope<<<4096, 256, 0, stream>>>(qf, gq, cs, sn, qb, cl2);
  k_normrope<<<4096, 256, 0, stream>>>(kf, gk, cs, sn, kb, 1.0f);
  k_tv<<<dim3(4, 64, 32), dim3(32, 8), 0, stream>>>(vb, vt);

  k_flash<<<1024, 256, 0, stream>>>(qb, kb, vt, On0, On1, Lf);
  k_merge<<<4096, 256, 0, stream>>>(On0, On1, Lf, attn);

  k_gemm<2><<<dim3(16, 32), 512, 0, stream>>>(attn, woT, bo, outf, outb, nullptr);
  k_gemm<3><<<dim3(16, 32), 512, 0, stream>>>(outb, wgT, bg, (float*)d_out, nullptr, outf);
}

// Round 10
// 486.568 us; speedup vs baseline: 1.0265x; 1.0265x over previous
//
#include <hip/hip_runtime.h>
#include <stdint.h>

typedef unsigned short ushort_t;
typedef __attribute__((ext_vector_type(8))) short bf16x8;
typedef __attribute__((ext_vector_type(4))) float f32x4;
typedef __attribute__((ext_vector_type(16))) float f32x16;
typedef __attribute__((ext_vector_type(4))) unsigned short u16x4;

#define B_ 2
#define T_ 2048
#define D_ 2048
#define H_ 16
#define HD_ 128
#define BT_ 4096

__device__ __forceinline__ ushort_t f2bf(float f) {
  unsigned u = __float_as_uint(f);
  u += 0x7FFFu + ((u >> 16) & 1u);   // RNE
  return (ushort_t)(u >> 16);
}

// pack two f32 -> u32 of 2 bf16 (RNE), low = first arg [T12 primitive, m214v22]
__device__ __forceinline__ unsigned cvtpk(float lo, float hi) {
  unsigned r;
  asm("v_cvt_pk_bf16_f32 %0, %1, %2" : "=v"(r) : "v"(lo), "v"(hi));
  return r;
}

__device__ __forceinline__ bf16x8 mk8(unsigned a, unsigned b, unsigned c, unsigned d) {
  union { unsigned u[4]; bf16x8 v; } x;
  x.u[0] = a; x.u[1] = b; x.u[2] = c; x.u[3] = d;
  return x.v;
}

__device__ __forceinline__ void async16(const void* g, void* l) {
  __builtin_amdgcn_global_load_lds(
      (const __attribute__((address_space(1))) unsigned int*)g,
      (__attribute__((address_space(3))) unsigned int*)l, 16, 0, 0);
}

// ---------------- elementwise cast x -> bf16 ----------------
__global__ void k_cast_x(const float* __restrict__ in, ushort_t* __restrict__ out) {
  int i = blockIdx.x * 256 + threadIdx.x;          // 4 elements per thread
  float4 v = ((const float4*)in)[i];
  u16x4 r = { f2bf(v.x), f2bf(v.y), f2bf(v.z), f2bf(v.w) };
  ((u16x4*)out)[i] = r;
}

// ---------------- fused weight transpose+cast x5: w[K][N] f32 -> wt[N][K] bf16 ----------------
__global__ void k_twT5(const float* __restrict__ wa, const float* __restrict__ wb,
                       const float* __restrict__ wc, const float* __restrict__ wd,
                       const float* __restrict__ we,
                       ushort_t* __restrict__ ta, ushort_t* __restrict__ tb,
                       ushort_t* __restrict__ tc, ushort_t* __restrict__ td,
                       ushort_t* __restrict__ te) {
  const float* w; ushort_t* wt;
  switch (blockIdx.z) {
    case 0: w = wa; wt = ta; break;
    case 1: w = wb; wt = tb; break;
    case 2: w = wc; wt = tc; break;
    case 3: w = wd; wt = td; break;
    default: w = we; wt = te; break;
  }
  __shared__ float tile[32][33];
  int tx = threadIdx.x, ty = threadIdx.y;
  int x = blockIdx.x * 32 + tx;        // N index
  int y0 = blockIdx.y * 32;            // K index
#pragma unroll
  for (int k = 0; k < 4; ++k)
    tile[ty + k * 8][tx] = w[(size_t)(y0 + ty + k * 8) * D_ + x];
  __syncthreads();
  int ox = blockIdx.y * 32 + tx;       // K contiguous on write
  int oy0 = blockIdx.x * 32;           // N
#pragma unroll
  for (int k = 0; k < 4; ++k)
    wt[(size_t)(oy0 + ty + k * 8) * D_ + ox] = f2bf(tile[tx][ty + k * 8]);
}

// ---------------- fused QKV GEMM: C[4096][6144] = xb * [wqT;wkT;wvT]^T + bias ----------------
// (measured R9: ~840 TF vs 600 TF for three separate launches)
__global__ __launch_bounds__(512) void k_gemm_qkv(
    const ushort_t* __restrict__ A, const ushort_t* __restrict__ Bt,
    const float* __restrict__ bq, const float* __restrict__ bk,
    const float* __restrict__ bv, float* __restrict__ qf,
    float* __restrict__ kf, ushort_t* __restrict__ vb) {
  __shared__ __align__(16) short As[2][128 * 64];
  __shared__ __align__(16) short Bs[2][128 * 64];
  const int tid = threadIdx.x;
  const int wid = tid >> 6, lane = tid & 63;
  const int l15 = lane & 15, kq = lane >> 4;
  const int m0 = (wid >> 2) * 64, n0 = (wid & 3) * 32;
  const int tileM = blockIdx.y * 128, tileN = blockIdx.x * 128;
  const int region = tileN >> 11;                  // 0:q 1:k 2:v
  const float* bias = region == 0 ? bq : (region == 1 ? bk : bv);

  f32x4 acc[4][2];
#pragma unroll
  for (int i = 0; i < 4; ++i)
#pragma unroll
    for (int j = 0; j < 2; ++j) acc[i][j] = (f32x4){0.f, 0.f, 0.f, 0.f};

  auto stage = [&](int sbuf, int k0) {
#pragma unroll
    for (int rr = 0; rr < 2; ++rr) {
      int c = rr * 512 + tid;
      int row = c >> 3, p = c & 7;
      int gc = p ^ (row & 7);
      async16(A + (size_t)(tileM + row) * D_ + k0 + gc * 8,
              &As[sbuf][(rr * 512 + wid * 64) * 8]);
      async16(Bt + (size_t)(tileN + row) * D_ + k0 + gc * 8,
              &Bs[sbuf][(rr * 512 + wid * 64) * 8]);
    }
  };

  stage(0, 0);
  for (int k0 = 0; k0 < D_; k0 += 64) {
    const int buf = (k0 >> 6) & 1;
    __asm__ volatile("s_waitcnt vmcnt(0)" ::: "memory");
    __builtin_amdgcn_s_barrier();
    if (k0 + 64 < D_) stage(buf ^ 1, k0 + 64);
#pragma unroll
    for (int half = 0; half < 2; ++half) {
      bf16x8 a[4], b[2];
#pragma unroll
      for (int i = 0; i < 4; ++i) {
        int row = m0 + i * 16 + l15;
        a[i] = *(const bf16x8*)&As[buf][row * 64 + ((half * 4 + kq) ^ (row & 7)) * 8];
      }
#pragma unroll
      for (int j = 0; j < 2; ++j) {
        int row = n0 + j * 16 + l15;
        b[j] = *(const bf16x8*)&Bs[buf][row * 64 + ((half * 4 + kq) ^ (row & 7)) * 8];
      }
#pragma unroll
      for (int i = 0; i < 4; ++i)
#pragma unroll
        for (int j = 0; j < 2; ++j)
          acc[i][j] = __builtin_amdgcn_mfma_f32_16x16x32_bf16(a[i], b[j], acc[i][j], 0, 0, 0);
    }
  }

#pragma unroll
  for (int i = 0; i < 4; ++i) {
#pragma unroll
    for (int j = 0; j < 2; ++j) {
#pragma unroll
      for (int r = 0; r < 4; ++r) {
        int gm = tileM + m0 + i * 16 + kq * 4 + r;
        int gn = tileN + n0 + j * 16 + l15;
        int gnl = gn & 2047;                       // col within region
        float val = acc[i][j][r] + bias[gnl];
        size_t idx = (size_t)gm * D_ + gnl;
        if (region == 0) qf[idx] = val;
        else if (region == 1) kf[idx] = val;
        else vb[idx] = f2bf(val);
      }
    }
  }
}

// ---------------- GEMM (wo/wg): C = A * Bt^T + bias ----------------
// EPI 2: store fp32 + bf16.  3: gate (out = aux * sigmoid(val))
template <int EPI>
__global__ __launch_bounds__(512) void k_gemm(
    const ushort_t* __restrict__ A, const ushort_t* __restrict__ Bt,
    const float* __restrict__ bias, float* __restrict__ outF,
    ushort_t* __restrict__ outB, const float* __restrict__ aux) {
  __shared__ __align__(16) short As[2][128 * 64];
  __shared__ __align__(16) short Bs[2][128 * 64];
  const int tid = threadIdx.x;
  const int wid = tid >> 6, lane = tid & 63;
  const int l15 = lane & 15, kq = lane >> 4;
  const int m0 = (wid >> 2) * 64, n0 = (wid & 3) * 32;
  const int tileM = blockIdx.y * 128, tileN = blockIdx.x * 128;

  f32x4 acc[4][2];
#pragma unroll
  for (int i = 0; i < 4; ++i)
#pragma unroll
    for (int j = 0; j < 2; ++j) acc[i][j] = (f32x4){0.f, 0.f, 0.f, 0.f};

  auto stage = [&](int sbuf, int k0) {
#pragma unroll
    for (int rr = 0; rr < 2; ++rr) {
      int c = rr * 512 + tid;
      int row = c >> 3, p = c & 7;
      int gc = p ^ (row & 7);
      async16(A + (size_t)(tileM + row) * D_ + k0 + gc * 8,
              &As[sbuf][(rr * 512 + wid * 64) * 8]);
      async16(Bt + (size_t)(tileN + row) * D_ + k0 + gc * 8,
              &Bs[sbuf][(rr * 512 + wid * 64) * 8]);
    }
  };

  stage(0, 0);
  for (int k0 = 0; k0 < D_; k0 += 64) {
    const int buf = (k0 >> 6) & 1;
    __asm__ volatile("s_waitcnt vmcnt(0)" ::: "memory");
    __builtin_amdgcn_s_barrier();
    if (k0 + 64 < D_) stage(buf ^ 1, k0 + 64);
#pragma unroll
    for (int half = 0; half < 2; ++half) {
      bf16x8 a[4], b[2];
#pragma unroll
      for (int i = 0; i < 4; ++i) {
        int row = m0 + i * 16 + l15;
        a[i] = *(const bf16x8*)&As[buf][row * 64 + ((half * 4 + kq) ^ (row & 7)) * 8];
      }
#pragma unroll
      for (int j = 0; j < 2; ++j) {
        int row = n0 + j * 16 + l15;
        b[j] = *(const bf16x8*)&Bs[buf][row * 64 + ((half * 4 + kq) ^ (row & 7)) * 8];
      }
#pragma unroll
      for (int i = 0; i < 4; ++i)
#pragma unroll
        for (int j = 0; j < 2; ++j)
          acc[i][j] = __builtin_amdgcn_mfma_f32_16x16x32_bf16(a[i], b[j], acc[i][j], 0, 0, 0);
    }
  }

#pragma unroll
  for (int i = 0; i < 4; ++i) {
#pragma unroll
    for (int j = 0; j < 2; ++j) {
#pragma unroll
      for (int r = 0; r < 4; ++r) {
        int gm = tileM + m0 + i * 16 + kq * 4 + r;
        int gn = tileN + n0 + j * 16 + l15;
        size_t idx = (size_t)gm * D_ + gn;
        float val = acc[i][j][r] + bias[gn];
        if (EPI == 2) {
          outF[idx] = val; outB[idx] = f2bf(val);
        } else {
          float sg = 1.f / (1.f + __expf(-val));
          outF[idx] = aux[idx] * sg;
        }
      }
    }
  }
}

// ---------------- fused RMSNorm (full D) + RoPE, fp32 in -> bf16 out (x oscale) ----------------
__global__ void k_normrope(const float* __restrict__ in, const float* __restrict__ g,
                           const float* __restrict__ cs, const float* __restrict__ sn,
                           ushort_t* __restrict__ out, float oscale) {
  const int row = blockIdx.x;            // 0..4095 = b*T + t
  const int t = row & (T_ - 1);
  const float* x = in + (size_t)row * D_;
  const int tid = threadIdx.x;
  float ss = 0.f;
#pragma unroll
  for (int i = tid; i < 512; i += 256) {
    float4 v = ((const float4*)x)[i];
    ss += v.x * v.x + v.y * v.y + v.z * v.z + v.w * v.w;
  }
#pragma unroll
  for (int off = 1; off < 64; off <<= 1) ss += __shfl_xor(ss, off, 64);
  __shared__ float part[4];
  if ((tid & 63) == 0) part[tid >> 6] = ss;
  __syncthreads();
  float rstd = rsqrtf((part[0] + part[1] + part[2] + part[3]) * (1.f / (float)D_) + 1e-6f);
  rstd *= oscale;                        // fold attention scale*log2e into Q
#pragma unroll
  for (int p = tid; p < 1024; p += 256) {
    int head = p >> 6, i = p & 63;
    int e1 = head * HD_ + i, e2 = e1 + 64;
    float x1 = x[e1] * rstd * g[e1];
    float x2 = x[e2] * rstd * g[e2];
    float c = cs[t * 64 + i], s = sn[t * 64 + i];
    out[(size_t)row * D_ + e1] = f2bf(x1 * c - s * x2);
    out[(size_t)row * D_ + e2] = f2bf(x2 * c + s * x1);
  }
}

// ---------------- V transpose per head: v[b][t][h*128+d] -> vt[bh][d][t] ----------------
__global__ void k_tv(const ushort_t* __restrict__ v, ushort_t* __restrict__ vt) {
  __shared__ ushort_t tile[32][33];
  int bh = blockIdx.z, b = bh >> 4, h = bh & 15;
  int tx = threadIdx.x, ty = threadIdx.y;
  int d = blockIdx.x * 32 + tx;
  int t0 = blockIdx.y * 32;
#pragma unroll
  for (int k = 0; k < 4; ++k)
    tile[ty + k * 8][tx] = v[(size_t)(b * T_ + t0 + ty + k * 8) * D_ + h * HD_ + d];
  __syncthreads();
  int ot = t0 + tx;
  int od0 = blockIdx.x * 32;
#pragma unroll
  for (int k = 0; k < 4; ++k)
    vt[((size_t)bh * HD_ + od0 + ty + k * 8) * T_ + ot] = tile[tx][ty + k * 8];
}

// ---------------- flash v12 (single-pass, consolidated): 32x32x16, swapped QK,
// single-chain QK accumulator, verified permlane in-register P transpose, K/V dbuf,
// one vmcnt(0)+barrier per iter, setprio, XCD swizzle. (R9's KV-split reverted:
// kernel is throughput-bound ~80% combined issue, TLP can't add throughput.)
__global__ __launch_bounds__(256) void k_flash(
    const ushort_t* __restrict__ Q, const ushort_t* __restrict__ K,
    const ushort_t* __restrict__ Vt, ushort_t* __restrict__ O) {
  __shared__ __align__(16) short Ks[2][32 * 128];   // [buf][key][d]   8 KB each
  __shared__ __align__(16) short Vs[2][128 * 32];   // [buf][d][key]   8 KB each

  const int tid = threadIdx.x;
  const int wv = tid >> 6, lane = tid & 63;
  const int l31 = lane & 31, hi = lane >> 5;
  const int flat = blockIdx.x;                       // 512 blocks
  const int swz = (flat & 7) * 64 + (flat >> 3);     // bijective XCD chunking (512=8*64)
  const int bh = swz >> 4, b = bh >> 4, h = bh & 15;
  const int q0 = (swz & 15) * 128;

  const ushort_t* kp[2];
  const ushort_t* vp[2];
#pragma unroll
  for (int rr = 0; rr < 2; ++rr) {
    int c = rr * 256 + tid;
    int krow = c >> 4, kc = (c & 15) ^ (krow & 15);       // 16 chunks/row (128 d)
    kp[rr] = K + (size_t)(b * T_ + krow) * D_ + h * HD_ + kc * 8;
    int drow = c >> 2, vc = (c & 3) ^ ((drow >> 1) & 3);  // 4 chunks/row (32 keys)
    vp[rr] = Vt + ((size_t)bh * HD_ + drow) * T_ + vc * 8;
  }

  // Q B-frags in registers: wave owns 32 q-rows (q0 + wv*32 + l31); scale pre-folded.
  bf16x8 qa[8];
  {
    const ushort_t* qp = Q + (size_t)(b * T_ + q0 + wv * 32 + l31) * D_ + h * HD_ + hi * 8;
#pragma unroll
    for (int kk = 0; kk < 8; ++kk) qa[kk] = *(const bf16x8*)(qp + kk * 16);
  }

  f32x16 o[4];
#pragma unroll
  for (int dt = 0; dt < 4; ++dt)
#pragma unroll
    for (int e = 0; e < 16; ++e) o[dt][e] = 0.f;
  float lsum = 0.f;                      // partial denominator for q=l31 (16 of 32 keys)

  // prologue: stage K(0), V(0) into buf 0
#pragma unroll
  for (int rr = 0; rr < 2; ++rr)
    async16(kp[rr], &Ks[0][(rr * 256 + wv * 64) * 8]);
#pragma unroll
  for (int rr = 0; rr < 2; ++rr)
    async16(vp[rr], &Vs[0][(rr * 256 + wv * 64) * 8]);

  for (int kt = 0; kt < 64; ++kt) {
    const int buf = kt & 1;
    __asm__ volatile("s_waitcnt vmcnt(0)" ::: "memory");
    __builtin_amdgcn_s_barrier();

    if (kt + 1 < 64) {
#pragma unroll
      for (int rr = 0; rr < 2; ++rr)
        async16(kp[rr] + (size_t)(kt + 1) * 32 * D_, &Ks[buf ^ 1][(rr * 256 + wv * 64) * 8]);
#pragma unroll
      for (int rr = 0; rr < 2; ++rr)
        async16(vp[rr] + (size_t)(kt + 1) * 32, &Vs[buf ^ 1][(rr * 256 + wv * 64) * 8]);
    }

    // S^T = K*Q^T (A=K rows=keys, B=Q cols=q): D col = q = l31 (lane-local)
    f32x16 s;
#pragma unroll
    for (int e = 0; e < 16; ++e) s[e] = 0.f;
    __builtin_amdgcn_s_setprio(1);
#pragma unroll
    for (int kk = 0; kk < 8; ++kk) {
      bf16x8 kf = *(const bf16x8*)&Ks[buf][l31 * 128 + (((kk << 1) + hi) ^ (l31 & 15)) * 8];
      s = __builtin_amdgcn_mfma_f32_32x32x16_bf16(kf, qa[kk], s, 0, 0, 0);
    }
    __builtin_amdgcn_s_setprio(0);

    // fixed-max softmax (exp2 domain): lane-local partials, pack to bf16 words
    unsigned w[8];
#pragma unroll
    for (int j = 0; j < 8; ++j) {
      float pa = __builtin_amdgcn_exp2f(s[2 * j]);
      float pb = __builtin_amdgcn_exp2f(s[2 * j + 1]);
      lsum += pa + pb;
      w[j] = cvtpk(pa, pb);
    }

    // in-register P transpose (bit-verified R8): lo/hi half-wave exchange
    auto r02 = __builtin_amdgcn_permlane32_swap(w[0], w[2], false, false);
    auto r13 = __builtin_amdgcn_permlane32_swap(w[1], w[3], false, false);
    auto r46 = __builtin_amdgcn_permlane32_swap(w[4], w[6], false, false);
    auto r57 = __builtin_amdgcn_permlane32_swap(w[5], w[7], false, false);
    bf16x8 pf0 = mk8(r02[0], r13[0], r02[1], r13[1]);
    bf16x8 pf1 = mk8(r46[0], r57[0], r46[1], r57[1]);

    // O += P * V
    __builtin_amdgcn_s_setprio(1);
#pragma unroll
    for (int dt = 0; dt < 4; ++dt) {
      int vrow = dt * 32 + l31;
      bf16x8 vf0 = *(const bf16x8*)&Vs[buf][vrow * 32 + ((hi) ^ ((vrow >> 1) & 3)) * 8];
      o[dt] = __builtin_amdgcn_mfma_f32_32x32x16_bf16(pf0, vf0, o[dt], 0, 0, 0);
      bf16x8 vf1 = *(const bf16x8*)&Vs[buf][vrow * 32 + ((2 + hi) ^ ((vrow >> 1) & 3)) * 8];
      o[dt] = __builtin_amdgcn_mfma_f32_32x32x16_bf16(pf1, vf1, o[dt], 0, 0, 0);
    }
    __builtin_amdgcn_s_setprio(0);
  }

  // full denominator: lane covers 16 keys, partner lane^32 the other 16
  lsum += __shfl_xor(lsum, 32, 64);

  // store: o[dt][r] is O[q = (r&3)+8*(r>>2)+4*hi][d = dt*32 + l31]
#pragma unroll
  for (int r = 0; r < 16; ++r) {
    int qrow = (r & 3) + 8 * (r >> 2) + 4 * hi;
    float inv = 1.f / __shfl(lsum, qrow, 64);
    size_t row = (size_t)(b * T_ + q0 + wv * 32 + qrow);
#pragma unroll
    for (int dt = 0; dt < 4; ++dt)
      O[row * D_ + h * HD_ + dt * 32 + l31] = f2bf(o[dt][r] * inv);
  }
}

// ---------------- launch ----------------
extern "C" void kernel_launch(void* const* d_in, const int* in_sizes, int n_in,
                              void* d_out, int out_size, void* d_ws, size_t ws_size,
                              hipStream_t stream) {
  const float* x  = (const float*)d_in[0];
  const float* cs = (const float*)d_in[1];
  const float* sn = (const float*)d_in[2];
  const float* wq = (const float*)d_in[3];
  const float* bq = (const float*)d_in[4];
  const float* wk = (const float*)d_in[5];
  const float* bk = (const float*)d_in[6];
  const float* wv = (const float*)d_in[7];
  const float* bv = (const float*)d_in[8];
  const float* gq = (const float*)d_in[9];
  const float* gk = (const float*)d_in[10];
  const float* wo = (const float*)d_in[11];
  const float* bo = (const float*)d_in[12];
  const float* wg = (const float*)d_in[13];
  const float* bg = (const float*)d_in[14];

  char* ws = (char*)d_ws;
  const size_t SZ_BTD_BF = (size_t)BT_ * D_ * 2;   // 16 MB
  const size_t SZ_DD_BF  = (size_t)D_ * D_ * 2;    //  8 MB
  const size_t SZ_BTD_F  = (size_t)BT_ * D_ * 4;   // 32 MB

  size_t off = 0;
  ushort_t* xb  = (ushort_t*)(ws + off); off += SZ_BTD_BF;        // aliased as attn later
  ushort_t* wqT = (ushort_t*)(ws + off); off += SZ_DD_BF;         // wqT/wkT/wvT contiguous:
  ushort_t* wkT = (ushort_t*)(ws + off); off += SZ_DD_BF;         //   one 6144-row B matrix
  ushort_t* wvT = (ushort_t*)(ws + off); off += SZ_DD_BF;
  ushort_t* woT = (ushort_t*)(ws + off); off += SZ_DD_BF;
  ushort_t* wgT = (ushort_t*)(ws + off); off += SZ_DD_BF;
  float*    qf  = (float*)(ws + off);    off += SZ_BTD_F;         // aliased as outf later
  float*    kf  = (float*)(ws + off);    off += SZ_BTD_F;         // aliased as outb later
  ushort_t* vb  = (ushort_t*)(ws + off); off += SZ_BTD_BF;
  ushort_t* qb  = (ushort_t*)(ws + off); off += SZ_BTD_BF;
  ushort_t* kb  = (ushort_t*)(ws + off); off += SZ_BTD_BF;
  ushort_t* vt  = (ushort_t*)(ws + off); off += SZ_BTD_BF;
  ushort_t* attn = xb;            // xb dead after QKV GEMM
  float*    outf = qf;            // qf dead after norm_rope(q)
  ushort_t* outb = (ushort_t*)kf; // kf dead after norm_rope(k)

  const float cl2 = 0.08838834764831845f * 1.4426950408889634f;  // 1/sqrt(128)*log2e

  k_cast_x<<<8192, 256, 0, stream>>>(x, xb);
  k_twT5<<<dim3(64, 64, 5), dim3(32, 8), 0, stream>>>(wq, wk, wv, wo, wg,
                                                      wqT, wkT, wvT, woT, wgT);

  k_gemm_qkv<<<dim3(48, 32), 512, 0, stream>>>(xb, wqT, bq, bk, bv, qf, kf, vb);

  k_normrope<<<4096, 256, 0, stream>>>(qf, gq, cs, sn, qb, cl2);
  k_normrope<<<4096, 256, 0, stream>>>(kf, gk, cs, sn, kb, 1.0f);
  k_tv<<<dim3(4, 64, 32), dim3(32, 8), 0, stream>>>(vb, vt);

  k_flash<<<512, 256, 0, stream>>>(qb, kb, vt, attn);

  k_gemm<2><<<dim3(16, 32), 512, 0, stream>>>(attn, woT, bo, outf, outb, nullptr);
  k_gemm<3><<<dim3(16, 32), 512, 0, stream>>>(outb, wgT, bg, (float*)d_out, nullptr, outf);
}